// Round 4
// baseline (655.414 us; speedup 1.0000x reference)
//
#include <hip/hip_runtime.h>
#include <hip/hip_bf16.h>

#define BB 64
#define CC 512
#define NN 1024
#define CQ 64

typedef unsigned short ushort_t;
typedef __attribute__((ext_vector_type(8))) short short8;
typedef __attribute__((ext_vector_type(4))) float f32x4;

__device__ __forceinline__ ushort_t f2bf(float v) {
    __hip_bfloat16 h = __float2bfloat16(v);
    return *(ushort_t*)&h;
}
__device__ __forceinline__ float bf2f(ushort_t u) {
    __hip_bfloat16 h;
    *(ushort_t*)&h = u;
    return __bfloat162float(h);
}
__device__ __forceinline__ void async_cp16(const void* g, void* l) {
    __builtin_amdgcn_global_load_lds(
        (const __attribute__((address_space(1))) unsigned int*)g,
        (__attribute__((address_space(3))) unsigned int*)l, 16, 0, 0);
}

// ---------------------------------------------------------------------------
// prep_w: split [Wq;Wk;Wv] (640x512 fp32) into whi bf16 (640 rows) and
// wlo bf16 (first 128 rows only).
// ---------------------------------------------------------------------------
__global__ __launch_bounds__(256) void prep_w(
    const float* __restrict__ Wq, const float* __restrict__ Wk,
    const float* __restrict__ Wv, ushort_t* __restrict__ whi,
    ushort_t* __restrict__ wlo)
{
    const int i = blockIdx.x * 256 + threadIdx.x;  // over 640*512
    if (i >= 640 * 512) return;
    float v;
    if (i < 32768)      v = Wq[i];
    else if (i < 65536) v = Wk[i - 32768];
    else                v = Wv[i - 65536];
    const ushort_t hu = f2bf(v);
    whi[i] = hu;
    if (i < 65536) wlo[i] = f2bf(v - bf2f(hu));
}

// ---------------------------------------------------------------------------
// xtrans: x[b][c][n] fp32 -> xthi/xtlo[b][n][c] bf16 (64x64 LDS tile transpose)
// ---------------------------------------------------------------------------
__global__ __launch_bounds__(256) void xtrans(
    const float* __restrict__ x, ushort_t* __restrict__ xthi,
    ushort_t* __restrict__ xtlo)
{
    __shared__ float ld[64][65];
    const int t = threadIdx.x;
    const int b = blockIdx.z, cb = blockIdx.y * 64, n0 = blockIdx.x * 64;

    #pragma unroll
    for (int p = 0; p < 4; ++p) {
        const int c = (t >> 4) + 16 * p;
        const float4 v = *(const float4*)&x[((size_t)b * CC + cb + c) * NN + n0 + (t & 15) * 4];
        ld[c][(t & 15) * 4 + 0] = v.x;
        ld[c][(t & 15) * 4 + 1] = v.y;
        ld[c][(t & 15) * 4 + 2] = v.z;
        ld[c][(t & 15) * 4 + 3] = v.w;
    }
    __syncthreads();

    #pragma unroll
    for (int p = 0; p < 2; ++p) {
        const int nr = (t >> 3) + 32 * p;
        ushort_t hs[8], ls[8];
        #pragma unroll
        for (int j = 0; j < 8; ++j) {
            const float v = ld[(t & 7) * 8 + j][nr];
            const ushort_t hu = f2bf(v);
            hs[j] = hu;
            ls[j] = f2bf(v - bf2f(hu));
        }
        uint4 H, L;
        H.x = hs[0] | ((unsigned)hs[1] << 16); H.y = hs[2] | ((unsigned)hs[3] << 16);
        H.z = hs[4] | ((unsigned)hs[5] << 16); H.w = hs[6] | ((unsigned)hs[7] << 16);
        L.x = ls[0] | ((unsigned)ls[1] << 16); L.y = ls[2] | ((unsigned)ls[3] << 16);
        L.z = ls[4] | ((unsigned)ls[5] << 16); L.w = ls[6] | ((unsigned)ls[7] << 16);
        const size_t idx = ((size_t)b * NN + n0 + nr) * CC + cb + (t & 7) * 8;
        *(uint4*)&xthi[idx] = H;
        *(uint4*)&xtlo[idx] = L;
    }
}

// ---------------------------------------------------------------------------
// fg_kernel: f,g = W[0:128] @ x (3-term hi/lo split), tile 128m x 64n, BK=64.
// Writes transposed fT/gT hi/lo bf16 planes into fgout.
// ---------------------------------------------------------------------------
__global__ __launch_bounds__(256) void fg_kernel(
    const ushort_t* __restrict__ whi, const ushort_t* __restrict__ wlo,
    const ushort_t* __restrict__ xthi, const ushort_t* __restrict__ xtlo,
    ushort_t* __restrict__ fgout)
{
    __shared__ __align__(16) ushort_t sWhi[128 * 64], sWlo[128 * 64];
    __shared__ __align__(16) ushort_t sXhi[64 * 64],  sXlo[64 * 64];
    const int t = threadIdx.x, l = t & 63, w = t >> 6;
    const int b = blockIdx.y, n0 = blockIdx.x * 64;
    const int wr = w >> 1, wc = w & 1;   // wr: 0=f rows 0..63, 1=g rows 64..127
    f32x4 acc[4][2] = {};

    const int srow = t >> 3;            // + p*32
    const int scol = (t & 7) * 8;

    for (int kt = 0; kt < 8; ++kt) {
        const int k0 = kt * 64;
        #pragma unroll
        for (int p = 0; p < 4; ++p) {
            const int row = p * 32 + srow;
            async_cp16(whi + (size_t)row * CC + k0 + scol, (char*)sWhi + p * 4096 + t * 16);
            async_cp16(wlo + (size_t)row * CC + k0 + scol, (char*)sWlo + p * 4096 + t * 16);
        }
        #pragma unroll
        for (int p = 0; p < 2; ++p) {
            const int row = p * 32 + srow;
            async_cp16(xthi + ((size_t)b * NN + n0 + row) * CC + k0 + scol,
                       (char*)sXhi + p * 4096 + t * 16);
            async_cp16(xtlo + ((size_t)b * NN + n0 + row) * CC + k0 + scol,
                       (char*)sXlo + p * 4096 + t * 16);
        }
        __syncthreads();
        #pragma unroll
        for (int kc = 0; kc < 2; ++kc) {
            const int fo = kc * 32 + (l >> 4) * 8;
            short8 ah[4], al[4], bh[2], bl[2];
            #pragma unroll
            for (int i = 0; i < 4; ++i) {
                ah[i] = *(const short8*)&sWhi[(wr * 64 + i * 16 + (l & 15)) * 64 + fo];
                al[i] = *(const short8*)&sWlo[(wr * 64 + i * 16 + (l & 15)) * 64 + fo];
            }
            #pragma unroll
            for (int j = 0; j < 2; ++j) {
                bh[j] = *(const short8*)&sXhi[(wc * 32 + j * 16 + (l & 15)) * 64 + fo];
                bl[j] = *(const short8*)&sXlo[(wc * 32 + j * 16 + (l & 15)) * 64 + fo];
            }
            #pragma unroll
            for (int i = 0; i < 4; ++i)
                #pragma unroll
                for (int j = 0; j < 2; ++j) {
                    acc[i][j] = __builtin_amdgcn_mfma_f32_16x16x32_bf16(ah[i], bh[j], acc[i][j], 0, 0, 0);
                    acc[i][j] = __builtin_amdgcn_mfma_f32_16x16x32_bf16(ah[i], bl[j], acc[i][j], 0, 0, 0);
                    acc[i][j] = __builtin_amdgcn_mfma_f32_16x16x32_bf16(al[i], bh[j], acc[i][j], 0, 0, 0);
                }
        }
        __syncthreads();
    }

    // plane layout in fgout: [fThi | fTlo | gThi | gTlo], each 4194304 elems
    ushort_t* pThi = fgout + (size_t)wr * 8388608;
    ushort_t* pTlo = pThi + 4194304;
    #pragma unroll
    for (int i = 0; i < 4; ++i) {
        const int qb = i * 16 + (l >> 4) * 4;
        #pragma unroll
        for (int j = 0; j < 2; ++j) {
            const int n = n0 + wc * 32 + j * 16 + (l & 15);
            ushort_t hs[4], ls[4];
            #pragma unroll
            for (int r = 0; r < 4; ++r) {
                const float v = acc[i][j][r];
                const ushort_t hu = f2bf(v);
                hs[r] = hu;
                ls[r] = f2bf(v - bf2f(hu));
            }
            uint2 H, L;
            H.x = hs[0] | ((unsigned)hs[1] << 16); H.y = hs[2] | ((unsigned)hs[3] << 16);
            L.x = ls[0] | ((unsigned)ls[1] << 16); L.y = ls[2] | ((unsigned)ls[3] << 16);
            const size_t base = ((size_t)b * NN + n) * CQ + qb;
            *(uint2*)&pThi[base] = H;
            *(uint2*)&pTlo[base] = L;
        }
    }
}

// ---------------------------------------------------------------------------
// h_kernel: h = Wv(512x512) @ x per batch. 128x128 tile, BK=64, double-buffer.
// A = whi rows 128..639, B = xthi. Writes h[b][c][n] bf16.
// ---------------------------------------------------------------------------
__global__ __launch_bounds__(256) void h_kernel(
    const ushort_t* __restrict__ whi, const ushort_t* __restrict__ xthi,
    ushort_t* __restrict__ h)
{
    __shared__ __align__(16) ushort_t sA[2][128 * 64], sB[2][128 * 64];
    const int t = threadIdx.x, l = t & 63, w = t >> 6;
    const int id = blockIdx.x;
    const int wg = (id & 7) * 256 + (id >> 3);      // XCD-chunked (2048 % 8 == 0)
    const int cy = wg & 3, nx = (wg >> 2) & 7, b = wg >> 5;
    const int c0 = cy * 128, n0 = nx * 128;
    const int wr = w >> 1, wc = w & 1;
    f32x4 acc[4][4] = {};

    const int srow = t >> 3;
    const int scol = (t & 7) * 8;

    auto STAGE = [&](int buf, int kt) {
        const int k0 = kt * 64;
        #pragma unroll
        for (int p = 0; p < 4; ++p) {
            const int row = p * 32 + srow;
            async_cp16(whi + (size_t)(128 + c0 + row) * CC + k0 + scol,
                       (char*)sA[buf] + p * 4096 + t * 16);
            async_cp16(xthi + ((size_t)b * NN + n0 + row) * CC + k0 + scol,
                       (char*)sB[buf] + p * 4096 + t * 16);
        }
    };

    STAGE(0, 0);
    __syncthreads();
    int cur = 0;
    for (int kt = 0; kt < 8; ++kt) {
        if (kt < 7) STAGE(cur ^ 1, kt + 1);
        #pragma unroll
        for (int kc = 0; kc < 2; ++kc) {
            const int fo = kc * 32 + (l >> 4) * 8;
            short8 a[4], bb[4];
            #pragma unroll
            for (int i = 0; i < 4; ++i)
                a[i] = *(const short8*)&sA[cur][(wr * 64 + i * 16 + (l & 15)) * 64 + fo];
            #pragma unroll
            for (int j = 0; j < 4; ++j)
                bb[j] = *(const short8*)&sB[cur][(wc * 64 + j * 16 + (l & 15)) * 64 + fo];
            #pragma unroll
            for (int i = 0; i < 4; ++i)
                #pragma unroll
                for (int j = 0; j < 4; ++j)
                    acc[i][j] = __builtin_amdgcn_mfma_f32_16x16x32_bf16(a[i], bb[j], acc[i][j], 0, 0, 0);
        }
        __syncthreads();
        cur ^= 1;
    }

    #pragma unroll
    for (int i = 0; i < 4; ++i)
        #pragma unroll
        for (int j = 0; j < 4; ++j) {
            const int n = n0 + wc * 64 + j * 16 + (l & 15);
            #pragma unroll
            for (int r = 0; r < 4; ++r) {
                const int c = c0 + wr * 64 + i * 16 + (l >> 4) * 4 + r;
                h[((size_t)b * CC + c) * NN + n] = f2bf(acc[i][j][r]);
            }
        }
}

// ---------------------------------------------------------------------------
// scores: ST[m][n] = sum_q gT[m][q]*fT[n][q] (3-term hi/lo), leaky_relu,
// row softmax over n, mask renorm, write btT[b][m][n] bf16.
// ---------------------------------------------------------------------------
__global__ __launch_bounds__(256) void scores_kernel(
    const ushort_t* __restrict__ fgout, const float* __restrict__ mask,
    ushort_t* __restrict__ btT)
{
    const ushort_t* fThi = fgout;
    const ushort_t* fTlo = fgout + 4194304;
    const ushort_t* gThi = fgout + 8388608;
    const ushort_t* gTlo = fgout + 12582912;
    __shared__ float redm[4][16], redz[4][16], rede[4][16];
    const int t = threadIdx.x, l = t & 63, w = t >> 6;
    const int m0 = blockIdx.x * 16, b = blockIdx.y;

    short8 ah[2], al[2];
    #pragma unroll
    for (int kc = 0; kc < 2; ++kc) {
        const size_t off = ((size_t)b * NN + m0 + (l & 15)) * CQ + kc * 32 + (l >> 4) * 8;
        ah[kc] = *(const short8*)&gThi[off];
        al[kc] = *(const short8*)&gTlo[off];
    }
    float mk[16];
    #pragma unroll
    for (int st = 0; st < 16; ++st)
        mk[st] = mask[(size_t)b * NN + w * 256 + st * 16 + (l & 15)];

    f32x4 acc[16] = {};
    #pragma unroll
    for (int st = 0; st < 16; ++st) {
        const size_t nb = (size_t)b * NN + w * 256 + st * 16 + (l & 15);
        #pragma unroll
        for (int kc = 0; kc < 2; ++kc) {
            const size_t off = nb * CQ + kc * 32 + (l >> 4) * 8;
            const short8 bh = *(const short8*)&fThi[off];
            const short8 bl = *(const short8*)&fTlo[off];
            acc[st] = __builtin_amdgcn_mfma_f32_16x16x32_bf16(ah[kc], bh, acc[st], 0, 0, 0);
            acc[st] = __builtin_amdgcn_mfma_f32_16x16x32_bf16(ah[kc], bl, acc[st], 0, 0, 0);
            acc[st] = __builtin_amdgcn_mfma_f32_16x16x32_bf16(al[kc], bh, acc[st], 0, 0, 0);
        }
    }
    // leaky relu in place
    #pragma unroll
    for (int st = 0; st < 16; ++st)
        #pragma unroll
        for (int r = 0; r < 4; ++r) {
            const float s = acc[st][r];
            acc[st][r] = s >= 0.f ? s : 0.2f * s;
        }
    // row max (rows live at (l>>4)*4+r across 16 cols = lanes l&15)
    float M[4] = {-3.4e38f, -3.4e38f, -3.4e38f, -3.4e38f};
    #pragma unroll
    for (int st = 0; st < 16; ++st)
        #pragma unroll
        for (int r = 0; r < 4; ++r) M[r] = fmaxf(M[r], acc[st][r]);
    #pragma unroll
    for (int off = 1; off <= 8; off <<= 1)
        #pragma unroll
        for (int r = 0; r < 4; ++r) M[r] = fmaxf(M[r], __shfl_xor(M[r], off));
    if ((l & 15) == 0)
        #pragma unroll
        for (int r = 0; r < 4; ++r) redm[w][(l >> 4) * 4 + r] = M[r];
    __syncthreads();
    #pragma unroll
    for (int r = 0; r < 4; ++r) {
        const int row = (l >> 4) * 4 + r;
        M[r] = fmaxf(fmaxf(redm[0][row], redm[1][row]), fmaxf(redm[2][row], redm[3][row]));
    }
    // exp in place, accumulate sums
    float Z[4] = {}, E[4] = {};
    #pragma unroll
    for (int st = 0; st < 16; ++st)
        #pragma unroll
        for (int r = 0; r < 4; ++r) {
            const float e = __expf(acc[st][r] - M[r]);
            acc[st][r] = e;
            Z[r] += e;
            E[r] += e * mk[st];
        }
    #pragma unroll
    for (int off = 1; off <= 8; off <<= 1)
        #pragma unroll
        for (int r = 0; r < 4; ++r) {
            Z[r] += __shfl_xor(Z[r], off);
            E[r] += __shfl_xor(E[r], off);
        }
    if ((l & 15) == 0)
        #pragma unroll
        for (int r = 0; r < 4; ++r) {
            redz[w][(l >> 4) * 4 + r] = Z[r];
            rede[w][(l >> 4) * 4 + r] = E[r];
        }
    __syncthreads();
    float inv[4];
    #pragma unroll
    for (int r = 0; r < 4; ++r) {
        const int row = (l >> 4) * 4 + r;
        const float z = redz[0][row] + redz[1][row] + redz[2][row] + redz[3][row];
        const float e4 = rede[0][row] + rede[1][row] + rede[2][row] + rede[3][row];
        inv[r] = 1.0f / (e4 + 1e-6f * z);
    }
    #pragma unroll
    for (int st = 0; st < 16; ++st)
        #pragma unroll
        for (int r = 0; r < 4; ++r)
            btT[((size_t)b * NN + m0 + (l >> 4) * 4 + r) * NN + w * 256 + st * 16 + (l & 15)] =
                f2bf(acc[st][r] * mk[st] * inv[r]);
}

// ---------------------------------------------------------------------------
// pv: O[b][c][m] = gamma * (sum_n h[c][n]*btT[m][n]) * mask[m] + x[c][m]
// 128x128 tile, BK=64, double-buffered 2-phase, XCD-chunked grid.
// ---------------------------------------------------------------------------
__global__ __launch_bounds__(256) void pv_kernel(
    const ushort_t* __restrict__ h, const ushort_t* __restrict__ btT,
    const float* __restrict__ mask, const float* __restrict__ x,
    const float* __restrict__ gamma, float* __restrict__ out)
{
    __shared__ __align__(16) ushort_t sA[2][128 * 64], sB[2][128 * 64];
    const int t = threadIdx.x, l = t & 63, w = t >> 6;
    const int id = blockIdx.x;
    const int wg = (id & 7) * 256 + (id >> 3);      // XCD-chunked (2048 % 8 == 0)
    const int mx = wg & 7, cy = (wg >> 3) & 3, b = wg >> 5;
    const int mc0 = mx * 128, c0 = cy * 128;
    const int wr = w >> 1, wc = w & 1;
    f32x4 acc[4][4] = {};

    const int srow = t >> 3;
    const int scol = (t & 7) * 8;

    auto STAGE = [&](int buf, int kt) {
        const int k0 = kt * 64;
        #pragma unroll
        for (int p = 0; p < 4; ++p) {
            const int row = p * 32 + srow;
            async_cp16(h + ((size_t)b * CC + c0 + row) * NN + k0 + scol,
                       (char*)sA[buf] + p * 4096 + t * 16);
            async_cp16(btT + ((size_t)b * NN + mc0 + row) * NN + k0 + scol,
                       (char*)sB[buf] + p * 4096 + t * 16);
        }
    };

    STAGE(0, 0);
    __syncthreads();
    int cur = 0;
    for (int kt = 0; kt < 16; ++kt) {
        if (kt < 15) STAGE(cur ^ 1, kt + 1);
        #pragma unroll
        for (int kc = 0; kc < 2; ++kc) {
            const int fo = kc * 32 + (l >> 4) * 8;
            short8 a[4], bb[4];
            #pragma unroll
            for (int i = 0; i < 4; ++i)
                a[i] = *(const short8*)&sA[cur][(wr * 64 + i * 16 + (l & 15)) * 64 + fo];
            #pragma unroll
            for (int j = 0; j < 4; ++j)
                bb[j] = *(const short8*)&sB[cur][(wc * 64 + j * 16 + (l & 15)) * 64 + fo];
            #pragma unroll
            for (int i = 0; i < 4; ++i)
                #pragma unroll
                for (int j = 0; j < 4; ++j)
                    acc[i][j] = __builtin_amdgcn_mfma_f32_16x16x32_bf16(a[i], bb[j], acc[i][j], 0, 0, 0);
        }
        __syncthreads();
        cur ^= 1;
    }

    const float gm = gamma[0];
    #pragma unroll
    for (int j = 0; j < 4; ++j) {
        const int mc = mc0 + wc * 64 + j * 16 + (l & 15);
        const float mv = mask[(size_t)b * NN + mc];
        #pragma unroll
        for (int i = 0; i < 4; ++i) {
            const int cc = c0 + wr * 64 + i * 16 + (l >> 4) * 4;
            #pragma unroll
            for (int r = 0; r < 4; ++r) {
                const size_t o = ((size_t)b * CC + cc + r) * NN + mc;
                out[o] = gm * acc[i][j][r] * mv + x[o];
            }
        }
    }
}

extern "C" void kernel_launch(void* const* d_in, const int* in_sizes, int n_in,
                              void* d_out, int out_size, void* d_ws, size_t ws_size,
                              hipStream_t stream)
{
    const float* x     = (const float*)d_in[0];
    const float* mask  = (const float*)d_in[1];
    const float* Wq    = (const float*)d_in[2];
    const float* Wk    = (const float*)d_in[3];
    const float* Wv    = (const float*)d_in[4];
    const float* gamma = (const float*)d_in[5];
    float* out = (float*)d_out;

    // ws layout (~192.8 MB):
    //   [0, 64M):    xthi bf16 [B][N][C]      (later aliased by btT)
    //   [64M,128M):  xtlo bf16 [B][N][C]      (later aliased by btT)
    //   [128M,192M): h    bf16 [B][C][N]
    //   [192M,+):    whi (640x512), wlo (128x512) bf16
    // d_out scratch (first 33.5 MB, dead before pv): fThi|fTlo|gThi|gTlo
    char* ws = (char*)d_ws;
    ushort_t* xthi = (ushort_t*)ws;
    ushort_t* xtlo = (ushort_t*)(ws + 67108864);
    ushort_t* hbuf = (ushort_t*)(ws + 134217728);
    ushort_t* whi  = (ushort_t*)(ws + 201326592);
    ushort_t* wlo  = (ushort_t*)(ws + 201981952);
    ushort_t* btT  = (ushort_t*)ws;              // aliases xthi+xtlo
    ushort_t* fgout = (ushort_t*)d_out;          // scratch planes in d_out

    prep_w<<<dim3(1280), 256, 0, stream>>>(Wq, Wk, Wv, whi, wlo);
    xtrans<<<dim3(16, 8, 64), 256, 0, stream>>>(x, xthi, xtlo);
    fg_kernel<<<dim3(16, 64), 256, 0, stream>>>(whi, wlo, xthi, xtlo, fgout);
    h_kernel<<<dim3(2048), 256, 0, stream>>>(whi, xthi, hbuf);
    scores_kernel<<<dim3(64, 64), 256, 0, stream>>>(fgout, mask, btT);
    pv_kernel<<<dim3(2048), 256, 0, stream>>>(hbuf, btT, mask, x, gamma, out);
}

// Round 6
// 620.216 us; speedup vs baseline: 1.0568x; 1.0568x over previous
//
#include <hip/hip_runtime.h>
#include <hip/hip_bf16.h>

#define BB 64
#define CC 512
#define NN 1024
#define CQ 64

typedef unsigned short ushort_t;
typedef __attribute__((ext_vector_type(8))) short short8;
typedef __attribute__((ext_vector_type(4))) float f32x4;

__device__ __forceinline__ ushort_t f2bf(float v) {
    __hip_bfloat16 h = __float2bfloat16(v);
    return *(ushort_t*)&h;
}
__device__ __forceinline__ float bf2f(ushort_t u) {
    __hip_bfloat16 h;
    *(ushort_t*)&h = u;
    return __bfloat162float(h);
}
__device__ __forceinline__ void async_cp16(const void* g, void* l) {
    __builtin_amdgcn_global_load_lds(
        (const __attribute__((address_space(1))) unsigned int*)g,
        (__attribute__((address_space(3))) unsigned int*)l, 16, 0, 0);
}

// ---------------------------------------------------------------------------
// prep_w: split [Wq;Wk;Wv] (640x512 fp32) into whi bf16 (640 rows) and
// wlo bf16 (first 128 rows only).
// ---------------------------------------------------------------------------
__global__ __launch_bounds__(256) void prep_w(
    const float* __restrict__ Wq, const float* __restrict__ Wk,
    const float* __restrict__ Wv, ushort_t* __restrict__ whi,
    ushort_t* __restrict__ wlo)
{
    const int i = blockIdx.x * 256 + threadIdx.x;  // over 640*512
    if (i >= 640 * 512) return;
    float v;
    if (i < 32768)      v = Wq[i];
    else if (i < 65536) v = Wk[i - 32768];
    else                v = Wv[i - 65536];
    const ushort_t hu = f2bf(v);
    whi[i] = hu;
    if (i < 65536) wlo[i] = f2bf(v - bf2f(hu));
}

// ---------------------------------------------------------------------------
// xtrans: x[b][c][n] fp32 -> xthi/xtlo[b][n][c] bf16 (64x64 LDS tile transpose)
// ---------------------------------------------------------------------------
__global__ __launch_bounds__(256) void xtrans(
    const float* __restrict__ x, ushort_t* __restrict__ xthi,
    ushort_t* __restrict__ xtlo)
{
    __shared__ float ld[64][65];
    const int t = threadIdx.x;
    const int b = blockIdx.z, cb = blockIdx.y * 64, n0 = blockIdx.x * 64;

    #pragma unroll
    for (int p = 0; p < 4; ++p) {
        const int c = (t >> 4) + 16 * p;
        const float4 v = *(const float4*)&x[((size_t)b * CC + cb + c) * NN + n0 + (t & 15) * 4];
        ld[c][(t & 15) * 4 + 0] = v.x;
        ld[c][(t & 15) * 4 + 1] = v.y;
        ld[c][(t & 15) * 4 + 2] = v.z;
        ld[c][(t & 15) * 4 + 3] = v.w;
    }
    __syncthreads();

    #pragma unroll
    for (int p = 0; p < 2; ++p) {
        const int nr = (t >> 3) + 32 * p;
        ushort_t hs[8], ls[8];
        #pragma unroll
        for (int j = 0; j < 8; ++j) {
            const float v = ld[(t & 7) * 8 + j][nr];
            const ushort_t hu = f2bf(v);
            hs[j] = hu;
            ls[j] = f2bf(v - bf2f(hu));
        }
        uint4 H, L;
        H.x = hs[0] | ((unsigned)hs[1] << 16); H.y = hs[2] | ((unsigned)hs[3] << 16);
        H.z = hs[4] | ((unsigned)hs[5] << 16); H.w = hs[6] | ((unsigned)hs[7] << 16);
        L.x = ls[0] | ((unsigned)ls[1] << 16); L.y = ls[2] | ((unsigned)ls[3] << 16);
        L.z = ls[4] | ((unsigned)ls[5] << 16); L.w = ls[6] | ((unsigned)ls[7] << 16);
        const size_t idx = ((size_t)b * NN + n0 + nr) * CC + cb + (t & 7) * 8;
        *(uint4*)&xthi[idx] = H;
        *(uint4*)&xtlo[idx] = L;
    }
}

// ---------------------------------------------------------------------------
// fg_kernel: f,g = W[0:128] @ x (3-term hi/lo split), tile 128m x 64n, BK=64.
// Writes transposed fT/gT hi/lo bf16 planes into fgout.
// ---------------------------------------------------------------------------
__global__ __launch_bounds__(256) void fg_kernel(
    const ushort_t* __restrict__ whi, const ushort_t* __restrict__ wlo,
    const ushort_t* __restrict__ xthi, const ushort_t* __restrict__ xtlo,
    ushort_t* __restrict__ fgout)
{
    __shared__ __align__(16) ushort_t sWhi[128 * 64], sWlo[128 * 64];
    __shared__ __align__(16) ushort_t sXhi[64 * 64],  sXlo[64 * 64];
    const int t = threadIdx.x, l = t & 63, w = t >> 6;
    const int b = blockIdx.y, n0 = blockIdx.x * 64;
    const int wr = w >> 1, wc = w & 1;   // wr: 0=f rows 0..63, 1=g rows 64..127
    f32x4 acc[4][2] = {};

    const int srow = t >> 3;            // + p*32
    const int scol = (t & 7) * 8;

    for (int kt = 0; kt < 8; ++kt) {
        const int k0 = kt * 64;
        #pragma unroll
        for (int p = 0; p < 4; ++p) {
            const int row = p * 32 + srow;
            async_cp16(whi + (size_t)row * CC + k0 + scol, (char*)sWhi + p * 4096 + t * 16);
            async_cp16(wlo + (size_t)row * CC + k0 + scol, (char*)sWlo + p * 4096 + t * 16);
        }
        #pragma unroll
        for (int p = 0; p < 2; ++p) {
            const int row = p * 32 + srow;
            async_cp16(xthi + ((size_t)b * NN + n0 + row) * CC + k0 + scol,
                       (char*)sXhi + p * 4096 + t * 16);
            async_cp16(xtlo + ((size_t)b * NN + n0 + row) * CC + k0 + scol,
                       (char*)sXlo + p * 4096 + t * 16);
        }
        __syncthreads();
        #pragma unroll
        for (int kc = 0; kc < 2; ++kc) {
            const int fo = kc * 32 + (l >> 4) * 8;
            short8 ah[4], al[4], bh[2], bl[2];
            #pragma unroll
            for (int i = 0; i < 4; ++i) {
                ah[i] = *(const short8*)&sWhi[(wr * 64 + i * 16 + (l & 15)) * 64 + fo];
                al[i] = *(const short8*)&sWlo[(wr * 64 + i * 16 + (l & 15)) * 64 + fo];
            }
            #pragma unroll
            for (int j = 0; j < 2; ++j) {
                bh[j] = *(const short8*)&sXhi[(wc * 32 + j * 16 + (l & 15)) * 64 + fo];
                bl[j] = *(const short8*)&sXlo[(wc * 32 + j * 16 + (l & 15)) * 64 + fo];
            }
            #pragma unroll
            for (int i = 0; i < 4; ++i)
                #pragma unroll
                for (int j = 0; j < 2; ++j) {
                    acc[i][j] = __builtin_amdgcn_mfma_f32_16x16x32_bf16(ah[i], bh[j], acc[i][j], 0, 0, 0);
                    acc[i][j] = __builtin_amdgcn_mfma_f32_16x16x32_bf16(ah[i], bl[j], acc[i][j], 0, 0, 0);
                    acc[i][j] = __builtin_amdgcn_mfma_f32_16x16x32_bf16(al[i], bh[j], acc[i][j], 0, 0, 0);
                }
        }
        __syncthreads();
    }

    // plane layout in fgout: [fThi | fTlo | gThi | gTlo], each 4194304 elems
    ushort_t* pThi = fgout + (size_t)wr * 8388608;
    ushort_t* pTlo = pThi + 4194304;
    #pragma unroll
    for (int i = 0; i < 4; ++i) {
        const int qb = i * 16 + (l >> 4) * 4;
        #pragma unroll
        for (int j = 0; j < 2; ++j) {
            const int n = n0 + wc * 32 + j * 16 + (l & 15);
            ushort_t hs[4], ls[4];
            #pragma unroll
            for (int r = 0; r < 4; ++r) {
                const float v = acc[i][j][r];
                const ushort_t hu = f2bf(v);
                hs[r] = hu;
                ls[r] = f2bf(v - bf2f(hu));
            }
            uint2 H, L;
            H.x = hs[0] | ((unsigned)hs[1] << 16); H.y = hs[2] | ((unsigned)hs[3] << 16);
            L.x = ls[0] | ((unsigned)ls[1] << 16); L.y = ls[2] | ((unsigned)ls[3] << 16);
            const size_t base = ((size_t)b * NN + n) * CQ + qb;
            *(uint2*)&pThi[base] = H;
            *(uint2*)&pTlo[base] = L;
        }
    }
}

// ---------------------------------------------------------------------------
// h_kernel: h = Wv(512x512) @ x per batch. 128x128 tile, BK=64,
// single-buffer 2-barrier (m97 structure), XCD-chunked grid.
// ---------------------------------------------------------------------------
__global__ __launch_bounds__(256) void h_kernel(
    const ushort_t* __restrict__ whi, const ushort_t* __restrict__ xthi,
    ushort_t* __restrict__ h)
{
    __shared__ __align__(16) ushort_t sA[128 * 64], sB[128 * 64];
    const int t = threadIdx.x, l = t & 63, w = t >> 6;
    const int id = blockIdx.x;
    const int wg = (id & 7) * 256 + (id >> 3);      // XCD-chunked (2048 % 8 == 0)
    const int cy = wg & 3, nx = (wg >> 2) & 7, b = wg >> 5;
    const int c0 = cy * 128, n0 = nx * 128;
    const int wr = w >> 1, wc = w & 1;
    f32x4 acc[4][4] = {};

    const int srow = t >> 3;
    const int scol = (t & 7) * 8;

    for (int kt = 0; kt < 8; ++kt) {
        const int k0 = kt * 64;
        #pragma unroll
        for (int p = 0; p < 4; ++p) {
            const int row = p * 32 + srow;
            async_cp16(whi + (size_t)(128 + c0 + row) * CC + k0 + scol,
                       (char*)sA + p * 4096 + t * 16);
            async_cp16(xthi + ((size_t)b * NN + n0 + row) * CC + k0 + scol,
                       (char*)sB + p * 4096 + t * 16);
        }
        __syncthreads();
        #pragma unroll
        for (int kc = 0; kc < 2; ++kc) {
            const int fo = kc * 32 + (l >> 4) * 8;
            short8 a[4], bb[4];
            #pragma unroll
            for (int i = 0; i < 4; ++i)
                a[i] = *(const short8*)&sA[(wr * 64 + i * 16 + (l & 15)) * 64 + fo];
            #pragma unroll
            for (int j = 0; j < 4; ++j)
                bb[j] = *(const short8*)&sB[(wc * 64 + j * 16 + (l & 15)) * 64 + fo];
            #pragma unroll
            for (int i = 0; i < 4; ++i)
                #pragma unroll
                for (int j = 0; j < 4; ++j)
                    acc[i][j] = __builtin_amdgcn_mfma_f32_16x16x32_bf16(a[i], bb[j], acc[i][j], 0, 0, 0);
        }
        __syncthreads();
    }

    #pragma unroll
    for (int i = 0; i < 4; ++i)
        #pragma unroll
        for (int j = 0; j < 4; ++j) {
            const int n = n0 + wc * 64 + j * 16 + (l & 15);
            #pragma unroll
            for (int r = 0; r < 4; ++r) {
                const int c = c0 + wr * 64 + i * 16 + (l >> 4) * 4 + r;
                h[((size_t)b * CC + c) * NN + n] = f2bf(acc[i][j][r]);
            }
        }
}

// ---------------------------------------------------------------------------
// scores: ST[m][n] = sum_q gT[m][q]*fT[n][q] (3-term hi/lo), leaky_relu,
// row softmax over n, mask renorm, write btT[b][m][n] bf16.
// ---------------------------------------------------------------------------
__global__ __launch_bounds__(256) void scores_kernel(
    const ushort_t* __restrict__ fgout, const float* __restrict__ mask,
    ushort_t* __restrict__ btT)
{
    const ushort_t* fThi = fgout;
    const ushort_t* fTlo = fgout + 4194304;
    const ushort_t* gThi = fgout + 8388608;
    const ushort_t* gTlo = fgout + 12582912;
    __shared__ float redm[4][16], redz[4][16], rede[4][16];
    const int t = threadIdx.x, l = t & 63, w = t >> 6;
    const int m0 = blockIdx.x * 16, b = blockIdx.y;

    short8 ah[2], al[2];
    #pragma unroll
    for (int kc = 0; kc < 2; ++kc) {
        const size_t off = ((size_t)b * NN + m0 + (l & 15)) * CQ + kc * 32 + (l >> 4) * 8;
        ah[kc] = *(const short8*)&gThi[off];
        al[kc] = *(const short8*)&gTlo[off];
    }
    float mk[16];
    #pragma unroll
    for (int st = 0; st < 16; ++st)
        mk[st] = mask[(size_t)b * NN + w * 256 + st * 16 + (l & 15)];

    f32x4 acc[16] = {};
    #pragma unroll
    for (int st = 0; st < 16; ++st) {
        const size_t nb = (size_t)b * NN + w * 256 + st * 16 + (l & 15);
        #pragma unroll
        for (int kc = 0; kc < 2; ++kc) {
            const size_t off = nb * CQ + kc * 32 + (l >> 4) * 8;
            const short8 bh = *(const short8*)&fThi[off];
            const short8 bl = *(const short8*)&fTlo[off];
            acc[st] = __builtin_amdgcn_mfma_f32_16x16x32_bf16(ah[kc], bh, acc[st], 0, 0, 0);
            acc[st] = __builtin_amdgcn_mfma_f32_16x16x32_bf16(ah[kc], bl, acc[st], 0, 0, 0);
            acc[st] = __builtin_amdgcn_mfma_f32_16x16x32_bf16(al[kc], bh, acc[st], 0, 0, 0);
        }
    }
    // leaky relu in place
    #pragma unroll
    for (int st = 0; st < 16; ++st)
        #pragma unroll
        for (int r = 0; r < 4; ++r) {
            const float s = acc[st][r];
            acc[st][r] = s >= 0.f ? s : 0.2f * s;
        }
    // row max (rows live at (l>>4)*4+r across 16 cols = lanes l&15)
    float M[4] = {-3.4e38f, -3.4e38f, -3.4e38f, -3.4e38f};
    #pragma unroll
    for (int st = 0; st < 16; ++st)
        #pragma unroll
        for (int r = 0; r < 4; ++r) M[r] = fmaxf(M[r], acc[st][r]);
    #pragma unroll
    for (int off = 1; off <= 8; off <<= 1)
        #pragma unroll
        for (int r = 0; r < 4; ++r) M[r] = fmaxf(M[r], __shfl_xor(M[r], off));
    if ((l & 15) == 0)
        #pragma unroll
        for (int r = 0; r < 4; ++r) redm[w][(l >> 4) * 4 + r] = M[r];
    __syncthreads();
    #pragma unroll
    for (int r = 0; r < 4; ++r) {
        const int row = (l >> 4) * 4 + r;
        M[r] = fmaxf(fmaxf(redm[0][row], redm[1][row]), fmaxf(redm[2][row], redm[3][row]));
    }
    // exp in place, accumulate sums
    float Z[4] = {}, E[4] = {};
    #pragma unroll
    for (int st = 0; st < 16; ++st)
        #pragma unroll
        for (int r = 0; r < 4; ++r) {
            const float e = __expf(acc[st][r] - M[r]);
            acc[st][r] = e;
            Z[r] += e;
            E[r] += e * mk[st];
        }
    #pragma unroll
    for (int off = 1; off <= 8; off <<= 1)
        #pragma unroll
        for (int r = 0; r < 4; ++r) {
            Z[r] += __shfl_xor(Z[r], off);
            E[r] += __shfl_xor(E[r], off);
        }
    if ((l & 15) == 0)
        #pragma unroll
        for (int r = 0; r < 4; ++r) {
            redz[w][(l >> 4) * 4 + r] = Z[r];
            rede[w][(l >> 4) * 4 + r] = E[r];
        }
    __syncthreads();
    float inv[4];
    #pragma unroll
    for (int r = 0; r < 4; ++r) {
        const int row = (l >> 4) * 4 + r;
        const float z = redz[0][row] + redz[1][row] + redz[2][row] + redz[3][row];
        const float e4 = rede[0][row] + rede[1][row] + rede[2][row] + rede[3][row];
        inv[r] = 1.0f / (e4 + 1e-6f * z);
    }
    #pragma unroll
    for (int st = 0; st < 16; ++st)
        #pragma unroll
        for (int r = 0; r < 4; ++r)
            btT[((size_t)b * NN + m0 + (l >> 4) * 4 + r) * NN + w * 256 + st * 16 + (l & 15)] =
                f2bf(acc[st][r] * mk[st] * inv[r]);
}

// ---------------------------------------------------------------------------
// pv: O[b][c][m] = gamma * (sum_n h[c][n]*btT[m][n]) * mask[m] + x[c][m]
// 128x128 tile, BK=64, single-buffer 2-barrier (m97 structure), XCD-chunked.
// ---------------------------------------------------------------------------
__global__ __launch_bounds__(256) void pv_kernel(
    const ushort_t* __restrict__ h, const ushort_t* __restrict__ btT,
    const float* __restrict__ mask, const float* __restrict__ x,
    const float* __restrict__ gamma, float* __restrict__ out)
{
    __shared__ __align__(16) ushort_t sA[128 * 64], sB[128 * 64];
    const int t = threadIdx.x, l = t & 63, w = t >> 6;
    const int id = blockIdx.x;
    const int wg = (id & 7) * 256 + (id >> 3);      // XCD-chunked (2048 % 8 == 0)
    const int mx = wg & 7, cy = (wg >> 3) & 3, b = wg >> 5;
    const int mc0 = mx * 128, c0 = cy * 128;
    const int wr = w >> 1, wc = w & 1;
    f32x4 acc[4][4] = {};

    const int srow = t >> 3;
    const int scol = (t & 7) * 8;

    for (int kt = 0; kt < 16; ++kt) {
        const int k0 = kt * 64;
        #pragma unroll
        for (int p = 0; p < 4; ++p) {
            const int row = p * 32 + srow;
            async_cp16(h + ((size_t)b * CC + c0 + row) * NN + k0 + scol,
                       (char*)sA + p * 4096 + t * 16);
            async_cp16(btT + ((size_t)b * NN + mc0 + row) * NN + k0 + scol,
                       (char*)sB + p * 4096 + t * 16);
        }
        __syncthreads();
        #pragma unroll
        for (int kc = 0; kc < 2; ++kc) {
            const int fo = kc * 32 + (l >> 4) * 8;
            short8 a[4], bb[4];
            #pragma unroll
            for (int i = 0; i < 4; ++i)
                a[i] = *(const short8*)&sA[(wr * 64 + i * 16 + (l & 15)) * 64 + fo];
            #pragma unroll
            for (int j = 0; j < 4; ++j)
                bb[j] = *(const short8*)&sB[(wc * 64 + j * 16 + (l & 15)) * 64 + fo];
            #pragma unroll
            for (int i = 0; i < 4; ++i)
                #pragma unroll
                for (int j = 0; j < 4; ++j)
                    acc[i][j] = __builtin_amdgcn_mfma_f32_16x16x32_bf16(a[i], bb[j], acc[i][j], 0, 0, 0);
        }
        __syncthreads();
    }

    const float gm = gamma[0];
    #pragma unroll
    for (int j = 0; j < 4; ++j) {
        const int mc = mc0 + wc * 64 + j * 16 + (l & 15);
        const float mv = mask[(size_t)b * NN + mc];
        #pragma unroll
        for (int i = 0; i < 4; ++i) {
            const int cc = c0 + wr * 64 + i * 16 + (l >> 4) * 4;
            #pragma unroll
            for (int r = 0; r < 4; ++r) {
                const size_t o = ((size_t)b * CC + cc + r) * NN + mc;
                out[o] = gm * acc[i][j][r] * mv + x[o];
            }
        }
    }
}

extern "C" void kernel_launch(void* const* d_in, const int* in_sizes, int n_in,
                              void* d_out, int out_size, void* d_ws, size_t ws_size,
                              hipStream_t stream)
{
    const float* x     = (const float*)d_in[0];
    const float* mask  = (const float*)d_in[1];
    const float* Wq    = (const float*)d_in[2];
    const float* Wk    = (const float*)d_in[3];
    const float* Wv    = (const float*)d_in[4];
    const float* gamma = (const float*)d_in[5];
    float* out = (float*)d_out;

    // ws layout (~192.8 MB):
    //   [0, 64M):    xthi bf16 [B][N][C]      (later aliased by btT)
    //   [64M,128M):  xtlo bf16 [B][N][C]      (later aliased by btT)
    //   [128M,192M): h    bf16 [B][C][N]
    //   [192M,+):    whi (640x512), wlo (128x512) bf16
    // d_out scratch (first 33.5 MB, dead before pv): fThi|fTlo|gThi|gTlo
    char* ws = (char*)d_ws;
    ushort_t* xthi = (ushort_t*)ws;
    ushort_t* xtlo = (ushort_t*)(ws + 67108864);
    ushort_t* hbuf = (ushort_t*)(ws + 134217728);
    ushort_t* whi  = (ushort_t*)(ws + 201326592);
    ushort_t* wlo  = (ushort_t*)(ws + 201981952);
    ushort_t* btT  = (ushort_t*)ws;              // aliases xthi+xtlo
    ushort_t* fgout = (ushort_t*)d_out;          // scratch planes in d_out

    prep_w<<<dim3(1280), 256, 0, stream>>>(Wq, Wk, Wv, whi, wlo);
    xtrans<<<dim3(16, 8, 64), 256, 0, stream>>>(x, xthi, xtlo);
    fg_kernel<<<dim3(16, 64), 256, 0, stream>>>(whi, wlo, xthi, xtlo, fgout);
    h_kernel<<<dim3(2048), 256, 0, stream>>>(whi, xthi, hbuf);
    scores_kernel<<<dim3(64, 64), 256, 0, stream>>>(fgout, mask, btT);
    pv_kernel<<<dim3(2048), 256, 0, stream>>>(hbuf, btT, mask, x, gamma, out);
}